// Round 8
// baseline (172.895 us; speedup 1.0000x reference)
//
#include <hip/hip_runtime.h>

#define NB 16
#define NH 4
#define HD 128
#define HW 1024
#define CIN 512

typedef short s16x8 __attribute__((ext_vector_type(8)));
typedef short s16x4 __attribute__((ext_vector_type(4)));
typedef float f32x4 __attribute__((ext_vector_type(4)));

static __device__ __forceinline__ short f2bf(float f) {
    union { float f; unsigned u; } v; v.f = f;
    unsigned r = v.u + 0x7fffu + ((v.u >> 16) & 1u);   // round-to-nearest-even
    return (short)(r >> 16);
}

// async global->LDS, 16B per lane; LDS dest = wave-uniform base + lane*16
static __device__ __forceinline__ void gld16(const short* g, short* l) {
    __builtin_amdgcn_global_load_lds(
        (const __attribute__((address_space(1))) void*)g,
        (__attribute__((address_space(3))) void*)l, 16, 0, 0);
}

// ---------------------------------------------------------------------------
// prep: x[b][c][p] fp32 -> xT_sw[b][p][c] bf16, PRE-SWIZZLED (chunk ^= p&7)
//       W[o][c]   fp32 -> Wb_sw bf16, PRE-SWIZZLED (chunk ^= o&7)
// so qkv's global_load_lds (lane-linear LDS deposit) lands bank-conflict-free.
// ---------------------------------------------------------------------------
__global__ __launch_bounds__(256) void prep_xw(
    const float* __restrict__ x, const float* __restrict__ w,
    short* __restrict__ xT, short* __restrict__ Wb)
{
    int blk = blockIdx.x;
    if (blk < NB * 16 * 32) {                  // 8192 transpose tiles
        int b = blk >> 9, rem = blk & 511;
        int ct = rem >> 5, pt = rem & 31;      // 16 c-tiles x 32 p-tiles
        __shared__ float tile[32][33];
        int tc = threadIdx.x >> 5;             // 0..7
        int tp = threadIdx.x & 31;             // 0..31
        const float* xb = x + ((size_t)b * CIN + ct * 32) * HW + pt * 32;
        #pragma unroll
        for (int i = 0; i < 4; i++)
            tile[tc + i * 8][tp] = xb[(size_t)(tc + i * 8) * HW + tp];
        __syncthreads();
        int p = threadIdx.x >> 3, cq = threadIdx.x & 7;
        int cc = ct * 4 + (cq >> 1);
        int phys = (cc & ~7) | ((cc & 7) ^ (p & 7));
        short* xo = xT + ((size_t)b * HW + pt * 32 + p) * CIN + phys * 8 + (cq & 1) * 4;
        s16x4 o4 = { f2bf(tile[cq * 4 + 0][p]), f2bf(tile[cq * 4 + 1][p]),
                     f2bf(tile[cq * 4 + 2][p]), f2bf(tile[cq * 4 + 3][p]) };
        *reinterpret_cast<s16x4*>(xo) = o4;
    } else {
        int wb = blk - NB * 16 * 32;           // 0..767, 1024 elems each
        size_t base = (size_t)wb * 1024 + threadIdx.x * 4;
        const float4 v = *reinterpret_cast<const float4*>(w + base);
        int o = (int)(base >> 9);
        int col = (int)(base & 511);
        int cc = col >> 3;
        int phys = (cc & ~7) | ((cc & 7) ^ (o & 7));
        s16x4 o4 = { f2bf(v.x), f2bf(v.y), f2bf(v.z), f2bf(v.w) };
        *reinterpret_cast<s16x4*>(Wb + (size_t)o * 512 + phys * 8 + (col & 7)) = o4;
    }
}

// ---------------------------------------------------------------------------
// qkv projection GEMM, BK=64, global_load_lds staging + double-buffered LDS
// -> ONE barrier per K-step, no commit phase. Inputs pre-swizzled (chunk ^
// row&7) so lane-linear deposit == conflict-free frag layout.
// NOTE: LDS buffer pointers computed by arithmetic at use (never an
// initialized array of LDS pointers -> "static initializer" compile error).
//   s=0: Q = val * (128^-0.5 * log2e)     [p][d] linear
//   s=1: K' = val + pos                   [p][d] pre-swizzled chunk^(p&15)
//   s=2: Vt = val                         [d][p] pre-swizzled chunk^(d&7)
// ---------------------------------------------------------------------------
__global__ __launch_bounds__(256, 2) void qkv_proj(
    const short* __restrict__ xT, const short* __restrict__ Wb,
    const float* __restrict__ pos_h, const float* __restrict__ pos_w,
    short* __restrict__ Q, short* __restrict__ Kp, short* __restrict__ Vt)
{
    __shared__ __align__(16) short smem[32768];   // 64 KB: A[2]|B[2] slabs
    // layout (short offsets): A buf0 @0, A buf1 @8192, B buf0 @16384, B buf1 @24576
    short* vb = smem;                              // [128][136] V-epilogue reuse

    const int pt = blockIdx.x, ot = blockIdx.y, b = blockIdx.z;
    const int tid = threadIdx.x;
    const int wave = tid >> 6, lane = tid & 63;
    const int l16 = lane & 15, quad = lane >> 4;
    const int wm = (wave & 1) * 64, wn = (wave >> 1) * 64;
    const int o0 = ot * 128, p0 = pt * 128;

    const short* xb = xT + (size_t)b * HW * CIN;
    const short* ag = Wb + (size_t)(o0 + (lane >> 3)) * CIN + (lane & 7) * 8;
    const short* bg = xb + (size_t)(p0 + (lane >> 3)) * CIN + (lane & 7) * 8;

    f32x4 acc[4][4];
    #pragma unroll
    for (int i = 0; i < 4; i++)
        #pragma unroll
        for (int j = 0; j < 4; j++)
            acc[i][j] = f32x4{0.f, 0.f, 0.f, 0.f};

    // stage one 128x64 slab of A and B into buffer `buf`
    auto stage = [&](int kc, int buf) {
        short* Ad = smem + buf * 8192;
        short* Bd = smem + 16384 + buf * 8192;
        #pragma unroll
        for (int j = 0; j < 4; j++) {
            int rbase = j * 32 + wave * 8;
            gld16(ag + (size_t)rbase * CIN + kc, Ad + rbase * 64);
            gld16(bg + (size_t)rbase * CIN + kc, Bd + rbase * 64);
        }
    };

    stage(0, 0);
    __syncthreads();

    #pragma unroll 1
    for (int it = 0; it < 8; it++) {
        int cb = it & 1;
        if (it < 7) stage((it + 1) * 64, cb ^ 1);
        const short* As = smem + cb * 8192;
        const short* Bs = smem + 16384 + cb * 8192;
        #pragma unroll
        for (int kk = 0; kk < 2; kk++) {
            s16x8 aF[4], bF[4];
            #pragma unroll
            for (int mi = 0; mi < 4; mi++)
                aF[mi] = *(const s16x8*)(As + (wm + mi * 16 + l16) * 64
                                         + (((kk * 4 + quad) ^ (l16 & 7)) * 8));
            #pragma unroll
            for (int ni = 0; ni < 4; ni++)
                bF[ni] = *(const s16x8*)(Bs + (wn + ni * 16 + l16) * 64
                                         + (((kk * 4 + quad) ^ (l16 & 7)) * 8));
            #pragma unroll
            for (int mi = 0; mi < 4; mi++)
                #pragma unroll
                for (int ni = 0; ni < 4; ni++)
                    acc[mi][ni] = __builtin_amdgcn_mfma_f32_16x16x32_bf16(
                        aF[mi], bF[ni], acc[mi][ni], 0, 0, 0);
        }
        __syncthreads();
    }

    const int s = ot >> 2, h = ot & 3;
    const size_t bh = (size_t)(b * NH + h);

    if (s == 0) {
        const float qs = 0.08838834764831845f * 1.4426950408889634f; // scale*log2e
        short* Qb = Q + bh * (size_t)(HW * HD);
        #pragma unroll
        for (int mi = 0; mi < 4; mi++) {
            int d0 = wm + mi * 16 + quad * 4;
            #pragma unroll
            for (int ni = 0; ni < 4; ni++) {
                int p = p0 + wn + ni * 16 + l16;
                f32x4 a = acc[mi][ni];
                s16x4 o4 = { f2bf(a.x * qs), f2bf(a.y * qs),
                             f2bf(a.z * qs), f2bf(a.w * qs) };
                *reinterpret_cast<s16x4*>(Qb + (size_t)p * HD + d0) = o4;
            }
        }
    } else if (s == 1) {
        short* Kb = Kp + bh * (size_t)(HW * HD);
        #pragma unroll
        for (int mi = 0; mi < 4; mi++) {
            int d0 = wm + mi * 16 + quad * 4;
            int lc = d0 >> 3;
            #pragma unroll
            for (int ni = 0; ni < 4; ni++) {
                int p = p0 + wn + ni * 16 + l16;
                const float4 eh = *reinterpret_cast<const float4*>(pos_h + (p >> 5) * HD + d0);
                const float4 ew = *reinterpret_cast<const float4*>(pos_w + (p & 31) * HD + d0);
                f32x4 a = acc[mi][ni];
                s16x4 o4 = { f2bf(a.x + eh.x + ew.x), f2bf(a.y + eh.y + ew.y),
                             f2bf(a.z + eh.z + ew.z), f2bf(a.w + eh.w + ew.w) };
                int phys = lc ^ l16;           // p&15 == l16
                *reinterpret_cast<s16x4*>(Kb + (size_t)p * HD + phys * 8 + (d0 & 7)) = o4;
            }
        }
    } else {
        __syncthreads();   // done with As/Bs before vb overlay
        #pragma unroll
        for (int mi = 0; mi < 4; mi++) {
            int d0 = wm + mi * 16 + quad * 4;
            #pragma unroll
            for (int ni = 0; ni < 4; ni++) {
                int p = wn + ni * 16 + l16;
                f32x4 a = acc[mi][ni];
                vb[(d0 + 0) * 136 + p] = f2bf(a.x);
                vb[(d0 + 1) * 136 + p] = f2bf(a.y);
                vb[(d0 + 2) * 136 + p] = f2bf(a.z);
                vb[(d0 + 3) * 136 + p] = f2bf(a.w);
            }
        }
        __syncthreads();
        short* Vb = Vt + bh * (size_t)(HD * HW);
        int d = tid >> 1, half = tid & 1;
        #pragma unroll
        for (int j = 0; j < 8; j++) {
            s16x8 v8 = *(const s16x8*)(vb + d * 136 + half * 64 + j * 8);
            int pj = j ^ (d & 7);              // pre-swizzle for attn glds
            *reinterpret_cast<s16x8*>(Vb + (size_t)d * HW + p0 + half * 64 + pj * 8) = v8;
        }
    }
}

// ---------------------------------------------------------------------------
// Fused attention: 4 waves x 32 Q-rows, kt = 64 keys x 16 iters.
// K/V staged via global_load_lds into DOUBLE-BUFFERED LDS -> exactly ONE
// barrier per kt, no commit phase; glds DMA lands during the compute window.
// K/V global layouts pre-swizzled by qkv so lane-linear deposits give
// conflict-free (<=2-way) b128 frag reads. S^T = K·Q^T -> packed s16x4
// P=exp2(S') into per-wave Ps strip -> b128 A-frags; l via MFMA vs ones;
// O += P·V. LDS 80 KB -> 2 blocks/CU. Grid 512 (bh = flat&63: XCD-affine).
// ---------------------------------------------------------------------------
__global__ __launch_bounds__(256, 2) void attn_fused(
    const short* __restrict__ Q, const short* __restrict__ Kp,
    const short* __restrict__ Vt, float* __restrict__ out)
{
    __shared__ short Ks[2][64 * 128];      // [key][physc], physc = c^(key&15)
    __shared__ short Vs[2][128 * 64];      // [d][physc],   physc = c^(d&7)
    __shared__ short Ps[4 * 32 * 64];      // per-wave [q][key], c^(q&7)

    const int flat = blockIdx.x;
    const int qt = flat >> 6;              // 0..7
    const int bh = flat & 63;              // XCD-affine: bh%8 == blockIdx%8
    const int tid = threadIdx.x;
    const int wave = tid >> 6, lane = tid & 63;
    const int l16 = lane & 15, quad = lane >> 4;

    const short* Qb = Q + (size_t)bh * (HW * HD);
    const short* Kb = Kp + (size_t)bh * (HW * HD);
    const short* Vb = Vt + (size_t)bh * (HD * HW);
    short* myP = Ps + wave * (32 * 64);

    const int q0 = qt * 128 + wave * 32;

    // Q fragments (B-operand for S^T): this wave's 32 rows, K=128 -> 2x4 frags
    s16x8 bQ[2][4];
    #pragma unroll
    for (int nt = 0; nt < 2; nt++)
        #pragma unroll
        for (int kk = 0; kk < 4; kk++)
            bQ[nt][kk] = *(const s16x8*)(Qb + (size_t)(q0 + nt * 16 + l16) * HD
                                         + kk * 32 + quad * 8);

    s16x8 ones;
    #pragma unroll
    for (int j = 0; j < 8; j++) ones[j] = (short)0x3F80;   // bf16 1.0

    f32x4 Oacc[2][8];
    #pragma unroll
    for (int mt = 0; mt < 2; mt++)
        #pragma unroll
        for (int dt = 0; dt < 8; dt++)
            Oacc[mt][dt] = f32x4{0.f, 0.f, 0.f, 0.f};
    f32x4 lacc[2] = { f32x4{0.f, 0.f, 0.f, 0.f}, f32x4{0.f, 0.f, 0.f, 0.f} };

    // glds lane geometry (thread-constant strides)
    const short* kg = Kb + (size_t)(lane >> 4) * HD + (lane & 15) * 8;
    const short* vg = Vb + (size_t)(lane >> 3) * HW + (lane & 7) * 8;

    auto stage = [&](int kt, int buf) {
        #pragma unroll
        for (int j = 0; j < 4; j++) {          // K: 16 rows/wave, 4 rows/call
            int rbase = j * 16 + wave * 4;
            gld16(kg + (size_t)(kt * 64 + rbase) * HD, &Ks[buf][rbase * 128]);
        }
        #pragma unroll
        for (int j = 0; j < 4; j++) {          // V: 32 d-rows/wave, 8/call
            int dbase = j * 32 + wave * 8;
            gld16(vg + (size_t)dbase * HW + kt * 64, &Vs[buf][dbase * 64]);
        }
    };

    stage(0, 0);
    __syncthreads();

    #pragma unroll 1
    for (int kt = 0; kt < 16; kt++) {
        int cb = kt & 1;
        if (kt < 15) stage(kt + 1, cb ^ 1);
        const short* KsC = &Ks[cb][0];
        const short* VsC = &Vs[cb][0];

        // ---- S^T: 64 keys x 32 qrows (aK shared across both q-tiles)
        f32x4 c[4][2];
        #pragma unroll
        for (int mtp = 0; mtp < 4; mtp++) {
            s16x8 aK[4];
            #pragma unroll
            for (int kk = 0; kk < 4; kk++)
                aK[kk] = *(const s16x8*)(KsC + (mtp * 16 + l16) * 128
                                         + (((kk * 4 + quad) ^ l16) * 8));
            c[mtp][0] = f32x4{0.f, 0.f, 0.f, 0.f};
            c[mtp][1] = f32x4{0.f, 0.f, 0.f, 0.f};
            #pragma unroll
            for (int kk = 0; kk < 4; kk++) {
                c[mtp][0] = __builtin_amdgcn_mfma_f32_16x16x32_bf16(
                    aK[kk], bQ[0][kk], c[mtp][0], 0, 0, 0);
                c[mtp][1] = __builtin_amdgcn_mfma_f32_16x16x32_bf16(
                    aK[kk], bQ[1][kk], c[mtp][1], 0, 0, 0);
            }
        }

        // ---- P = exp2(S') packed s16x4 writes (4 consecutive keys/lane)
        #pragma unroll
        for (int mtp = 0; mtp < 4; mtp++)
            #pragma unroll
            for (int nt = 0; nt < 2; nt++) {
                f32x4 pv = c[mtp][nt];
                s16x4 pp = { f2bf(__builtin_amdgcn_exp2f(pv[0])),
                             f2bf(__builtin_amdgcn_exp2f(pv[1])),
                             f2bf(__builtin_amdgcn_exp2f(pv[2])),
                             f2bf(__builtin_amdgcn_exp2f(pv[3])) };
                int q = nt * 16 + l16;
                int chunk = 2 * mtp + (quad >> 1);
                int phys = chunk ^ (l16 & 7);          // q&7 == l16&7
                *(s16x4*)(myP + q * 64 + phys * 8 + (quad & 1) * 4) = pp;
            }

        // ---- read P back as A-frags (in-wave DS ordering, no barrier)
        s16x8 aP[2][2];
        #pragma unroll
        for (int mt = 0; mt < 2; mt++)
            #pragma unroll
            for (int kp = 0; kp < 2; kp++) {
                int phys = (kp * 4 + quad) ^ (l16 & 7);
                aP[mt][kp] = *(const s16x8*)(myP + (mt * 16 + l16) * 64 + phys * 8);
            }

        // l += P * ones
        #pragma unroll
        for (int mt = 0; mt < 2; mt++)
            #pragma unroll
            for (int kp = 0; kp < 2; kp++)
                lacc[mt] = __builtin_amdgcn_mfma_f32_16x16x32_bf16(
                    aP[mt][kp], ones, lacc[mt], 0, 0, 0);

        // ---- O += P * V (each bV read feeds both mt)
        #pragma unroll
        for (int dt = 0; dt < 8; dt++) {
            s16x8 bV0 = *(const s16x8*)(VsC + (dt * 16 + l16) * 64
                                        + ((quad ^ (l16 & 7)) * 8));
            s16x8 bV1 = *(const s16x8*)(VsC + (dt * 16 + l16) * 64
                                        + (((4 + quad) ^ (l16 & 7)) * 8));
            #pragma unroll
            for (int mt = 0; mt < 2; mt++) {
                Oacc[mt][dt] = __builtin_amdgcn_mfma_f32_16x16x32_bf16(
                    aP[mt][0], bV0, Oacc[mt][dt], 0, 0, 0);
                Oacc[mt][dt] = __builtin_amdgcn_mfma_f32_16x16x32_bf16(
                    aP[mt][1], bV1, Oacc[mt][dt], 0, 0, 0);
            }
        }
        __syncthreads();   // single barrier: reads of cb done + glds(cb^1) drained
    }

    // epilogue: O/l, stored transposed -> out[b][h][d][p] FP32
    float* ob = out + (size_t)bh * (HD * HW);
    #pragma unroll
    for (int mt = 0; mt < 2; mt++) {
        float inv[4];
        #pragma unroll
        for (int r = 0; r < 4; r++) inv[r] = __builtin_amdgcn_rcpf(lacc[mt][r]);
        int prow = q0 + mt * 16 + quad * 4;
        #pragma unroll
        for (int dt = 0; dt < 8; dt++) {
            int d = dt * 16 + l16;
            f32x4 o = Oacc[mt][dt];
            float4 o4 = { o[0] * inv[0], o[1] * inv[1],
                          o[2] * inv[2], o[3] * inv[3] };
            *reinterpret_cast<float4*>(ob + (size_t)d * HW + prow) = o4;
        }
    }
}

// ---------------------------------------------------------------------------
extern "C" void kernel_launch(void* const* d_in, const int* in_sizes, int n_in,
                              void* d_out, int out_size, void* d_ws, size_t ws_size,
                              hipStream_t stream) {
    const float* x  = (const float*)d_in[0];
    const float* w  = (const float*)d_in[1];
    const float* ph = (const float*)d_in[2];
    const float* pw = (const float*)d_in[3];

    const size_t BHPD = (size_t)NB * NH * HW * HD;   // 8,388,608 elems
    short* Q    = (short*)d_ws;
    short* Kp   = Q + BHPD;
    short* Vt   = Kp + BHPD;
    short* xT   = Vt + BHPD;
    short* Wb   = xT + (size_t)NB * HW * CIN;
    float* outp = (float*)d_out;

    prep_xw<<<dim3(NB * 16 * 32 + 768), 256, 0, stream>>>(x, w, xT, Wb);
    qkv_proj<<<dim3(8, 12, NB), 256, 0, stream>>>(xT, Wb, ph, pw, Q, Kp, Vt);
    attn_fused<<<dim3(512), 256, 0, stream>>>(Q, Kp, Vt, outp);
}